// Round 9
// baseline (121.353 us; speedup 1.0000x reference)
//
#include <hip/hip_runtime.h>
#include <hip/hip_fp16.h>

// Deformable conv B=4 C=64 H=W=128 O=64 3x3 s1 p1 d1, DG=1.
// v9 = v8 with the x fp32->fp16 NHWC transform FUSED into the window staging
// (kills the 2048-block prep pass and its 24 MB HBM round trip). Window tile
// is loaded per chunk straight from NCHW fp32 x with coalesced plane reads,
// converted RN to fp16 in registers (numerics identical to v8's prep).

#define B_  4
#define C_  64
#define H_  128
#define W_  128
#define O_  64
#define HO_ 128
#define WO_ 128
#define HW_ (H_ * W_)
#define NCHUNK 8
#define NGW 12            // weight K-groups per chunk: 9 real taps + 3 zero
#define KSTEPS 3          // NGW*8 / 32
#define NT_ 32            // wo tile per block
#define NTASK (9 * NT_)   // 288 sampling tasks per chunk
#define SG  10            // sS groups per buffer: 9 taps + 1 zero pad
#define SBUF (SG * NT_ * 8)   // halves per buffer (2560 = 5 KB)
#define TR  16            // tile rows    (y in [ho-7, ho+9))
#define TC  48            // tile cols    (x in [woB-8, woB+40))
#define TSLOTS (TR * TC)  // 768 positions x 16 B = 12 KB

typedef _Float16 half8 __attribute__((ext_vector_type(8)));
typedef __attribute__((ext_vector_type(4))) float f32x4;

union H8 { float4 v; __half2 h2[4]; half8 v8; __half h[8]; };

// Weight transform only: wt fp16 [(ch*12+g)*64+o]*8+e  (g<9: tap g, else 0).
__global__ __launch_bounds__(256)
void prep(const float* __restrict__ w, __half* __restrict__ wt) {
    int t = blockIdx.x * 256 + threadIdx.x;   // 6144 total = 24 blocks
    if (t >= NCHUNK * NGW * O_) return;
    int o  = t & 63;
    int g  = (t >> 6) % NGW;
    int ch = (t >> 6) / NGW;
    union { __half h[8]; float4 v; } pk;
#pragma unroll
    for (int e = 0; e < 8; ++e)
        pk.h[e] = (g < 9) ? __float2half_rn(w[(o * C_ + ch * 8 + e) * 9 + g])
                          : __half(0.0f);
    *(float4*)(wt + (size_t)t * 8) = pk.v;
}

__global__ __launch_bounds__(256, 4)
void dcn_mfma(const float* __restrict__ x, const float* __restrict__ off,
              const __half* __restrict__ wt, const float* __restrict__ bias,
              float* __restrict__ out) {
    __shared__ __align__(16) _Float16 sS[2 * SBUF];   // 10 KB double-buffered
    __shared__ __align__(16) _Float16 sT[TSLOTS * 8]; // 12 KB x-window tile

    const int tid = threadIdx.x;
    const int bid = blockIdx.x;              // (b, ho, wo-quarter)
    const int w4  = bid & 3;
    const int ho  = (bid >> 2) & (HO_ - 1);
    const int b   = bid >> 9;
    const int woB = w4 * NT_;
    const int yorg = ho - 7;                 // tile origin (row)
    const int xorg = woB - 8;                // tile origin (col)

    // ---- bilinear metadata per (k, wo_local) task: tile-local coords + fallback ----
    int ty0_[2], ty1_[2], tx_[2], fb_[2];
    __half2 ua2_[2], ub2_[2], va2_[2], vb2_[2];
#pragma unroll
    for (int r = 0; r < 2; ++r) {
        int task = tid + r * 256;
        int tk = (task < NTASK) ? task : 0;
        int k  = tk >> 5;
        int wo = (tk & (NT_ - 1)) + woB;
        int ki = k / 3, kj = k - 3 * ki;
        float oy = off[(((b * 18) + 2 * k    ) * HO_ + ho) * WO_ + wo];
        float ox = off[(((b * 18) + 2 * k + 1) * HO_ + ho) * WO_ + wo];
        float py = (float)(ho - 1 + ki) + oy;
        float px = (float)(wo - 1 + kj) + ox;
        float y0f = floorf(py), x0f = floorf(px);
        int   y0 = (int)y0f,   x0 = (int)x0f;
        float ly = py - y0f,   lx = px - x0f;
        float hy = 1.f - ly,   hx = 1.f - lx;
        int y1 = y0 + 1, x1 = x0 + 1;
        float vy0 = (y0 >= 0 && y0 < H_) ? 1.f : 0.f;
        float vy1 = (y1 >= 0 && y1 < H_) ? 1.f : 0.f;
        float vx0 = (x0 >= 0 && x0 < W_) ? 1.f : 0.f;
        float vx1 = (x1 >= 0 && x1 < W_) ? 1.f : 0.f;
        int cy0 = min(max(y0, 0), H_ - 1), cy1 = min(max(y1, 0), H_ - 1);
        int cx0 = min(max(x0, 0), W_ - 1), cx1 = min(max(x1, 0), W_ - 1);
        int ax  = min(max(x0, 0), W_ - 2);
        float w00 = hy * hx * vy0 * vx0;
        float w01 = hy * lx * vy0 * vx1;
        float w10 = ly * hx * vy1 * vx0;
        float w11 = ly * lx * vy1 * vx1;
        float s0 = (cx0 != ax) ? 1.f : 0.f;
        float s1 = (cx1 != ax) ? 1.f : 0.f;
        ty0_[r] = cy0 - yorg;
        ty1_[r] = cy1 - yorg;
        tx_[r]  = ax - xorg;
        fb_[r]  = ((unsigned)ty0_[r] > (unsigned)(TR - 1)) |
                  ((unsigned)ty1_[r] > (unsigned)(TR - 1)) |
                  ((unsigned)tx_[r]  > (unsigned)(TC - 2));
        ua2_[r] = __float2half2_rn(w00 * (1.f - s0) + w01 * (1.f - s1));
        ub2_[r] = __float2half2_rn(w00 * s0 + w01 * s1);
        va2_[r] = __float2half2_rn(w10 * (1.f - s0) + w11 * (1.f - s1));
        vb2_[r] = __float2half2_rn(w10 * s0 + w11 * s1);
    }

    // ---- stage-slot global offsets (clamped), 3 slots/thread, dword units ----
    int gofs[3];
#pragma unroll
    for (int j = 0; j < 3; ++j) {
        int s  = tid + j * 256;
        int rr = s / TC, cc = s - rr * TC;
        int yc = min(max(yorg + rr, 0), H_ - 1);
        int xc = min(max(xorg + cc, 0), W_ - 1);
        gofs[j] = yc * W_ + xc;
    }

    // zero pad group (group 9) in both sS buffers: 128 dwords each
    if (tid < 128) {
        ((unsigned int*)&sS[9 * NT_ * 8])[tid]        = 0u;
        ((unsigned int*)&sS[SBUF + 9 * NT_ * 8])[tid] = 0u;
    }

    // ---- stage: fused transpose+cvt, NCHW fp32 -> fp16-octet LDS tile ----
    auto stage = [&](int ch) {
        const float* xb = x + ((size_t)(b * C_ + ch * 8)) * HW_;
        float4* tw = (float4*)sT;
#pragma unroll 1          // cap live staging registers (keep VGPR <= 64)
        for (int j = 0; j < 3; ++j) {
            const int g = gofs[j];
            float v[8];
#pragma unroll
            for (int e = 0; e < 8; ++e) v[e] = xb[e * HW_ + g];
            H8 pk;
#pragma unroll
            for (int e = 0; e < 8; ++e) pk.h[e] = __float2half_rn(v[e]);
            tw[tid + j * 256] = pk.v;
        }
    };

    // ---- sample: LDS-window bilinear gather + fp16 blend -> sS[parity] ----
    auto sample = [&](int ch) {
        _Float16* buf = sS + (ch & 1) * SBUF;
        const float4* tl = (const float4*)sT;
#pragma unroll
        for (int r = 0; r < 2; ++r) {
            int task = tid + r * 256;
            if (task < NTASK) {
                int k  = task >> 5;
                int wo = task & (NT_ - 1);
                H8 s;
                if (!fb_[r]) {
                    int a0 = ty0_[r] * TC + tx_[r];
                    int a1 = ty1_[r] * TC + tx_[r];
                    H8 q00, q01, q10, q11;
                    q00.v = tl[a0];  q01.v = tl[a0 + 1];
                    q10.v = tl[a1];  q11.v = tl[a1 + 1];
#pragma unroll
                    for (int j = 0; j < 4; ++j) {
                        __half2 t0 = __hmul2(ua2_[r], q00.h2[j]);
                        t0 = __hfma2(ub2_[r], q01.h2[j], t0);
                        t0 = __hfma2(va2_[r], q10.h2[j], t0);
                        t0 = __hfma2(vb2_[r], q11.h2[j], t0);
                        s.h2[j] = t0;
                    }
                } else {   // exact fp32 fallback, |offset| beyond window (~never)
                    const float* xb = x + ((size_t)(b * C_ + ch * 8)) * HW_;
                    int a0 = (ty0_[r] + yorg) * W_ + (tx_[r] + xorg);
                    int a1 = (ty1_[r] + yorg) * W_ + (tx_[r] + xorg);
                    float ua = __half2float(__low2half(ua2_[r]));
                    float ub = __half2float(__low2half(ub2_[r]));
                    float va = __half2float(__low2half(va2_[r]));
                    float vb = __half2float(__low2half(vb2_[r]));
#pragma unroll
                    for (int e = 0; e < 8; ++e) {
                        const float* xe = xb + e * HW_;
                        float sv = ua * xe[a0] + ub * xe[a0 + 1]
                                 + va * xe[a1] + vb * xe[a1 + 1];
                        s.h[e] = __float2half_rn(sv);
                    }
                }
                *(half8*)&buf[(k * NT_ + wo) * 8] = s.v8;
            }
        }
    };

    // ---- GEMM lane mapping: 2x2 wave split ----
    const int lane = tid & 63;
    const int wv   = tid >> 6;
    const int ow   = wv & 1;
    const int nw   = wv >> 1;
    const int quad = lane >> 4;
    const int l15  = lane & 15;

    f32x4 acc[2];
    acc[0] = (f32x4){0.f, 0.f, 0.f, 0.f};
    acc[1] = (f32x4){0.f, 0.f, 0.f, 0.f};

    auto mfma_chunk = [&](int ch) {
        const __half*   wc  = wt + (size_t)(ch * NGW) * O_ * 8;
        const _Float16* buf = sS + (ch & 1) * SBUF;
#pragma unroll
        for (int ks = 0; ks < KSTEPS; ++ks) {
            int g  = ks * 4 + quad;
            int gb = (g < 9) ? g : 9;            // groups 9..11 -> zero pad
            half8 bfr = *(const half8*)&buf[(gb * NT_ + nw * 16 + l15) * 8];
#pragma unroll
            for (int ot = 0; ot < 2; ++ot) {
                half8 afr = *(const half8*)(wc + (size_t)(g * O_ + ow * 32 + ot * 16 + l15) * 8);
                acc[ot] = __builtin_amdgcn_mfma_f32_16x16x32_f16(afr, bfr, acc[ot], 0, 0, 0);
            }
        }
    };

    for (int ch = 0; ch < NCHUNK; ++ch) {
        stage(ch);            // global fp32 -> fp16 tile (coalesced)
        __syncthreads();      // tile ready; sS[(ch-1)&1] fully written
        sample(ch);           // LDS gather -> sS[ch&1]
        if (ch > 0) mfma_chunk(ch - 1);
        __syncthreads();      // sample done: tile free, sS[ch&1] published
    }
    mfma_chunk(NCHUNK - 1);

    // ---- epilogue: C/D col = lane&15 (wo), row = quad*4+reg (o) ----
#pragma unroll
    for (int ot = 0; ot < 2; ++ot) {
        int wo = woB + nw * 16 + l15;
#pragma unroll
        for (int rg = 0; rg < 4; ++rg) {
            int o = ow * 32 + ot * 16 + quad * 4 + rg;
            out[(((size_t)(b * O_ + o)) * HO_ + ho) * WO_ + wo] = acc[ot][rg] + bias[o];
        }
    }
}

extern "C" void kernel_launch(void* const* d_in, const int* in_sizes, int n_in,
                              void* d_out, int out_size, void* d_ws, size_t ws_size,
                              hipStream_t stream) {
    const float* x    = (const float*)d_in[0];
    const float* off  = (const float*)d_in[1];
    const float* w    = (const float*)d_in[2];
    const float* bias = (const float*)d_in[3];
    float* out = (float*)d_out;

    __half* wt = (__half*)d_ws;                       // 98304 B

    hipLaunchKernelGGL(prep, dim3(24), dim3(256), 0, stream, w, wt);
    hipLaunchKernelGGL(dcn_mfma, dim3(B_ * HO_ * (WO_ / NT_)), dim3(256), 0, stream,
                       x, off, wt, bias, out);
}